// Round 3
// baseline (224.808 us; speedup 1.0000x reference)
//
#include <hip/hip_runtime.h>
#include <hip/hip_bf16.h>
#include <math.h>

#define D_MODEL 1024
#define NHEADS  16
#define DK      64
#define SEQ     2048
#define BATCH   2
#define MROWS   4096   // BATCH*SEQ
#define NQT2    (SEQ/128)  // 16 q-tiles of 128 rows

typedef unsigned short ushort_t;
using short8 = __attribute__((ext_vector_type(8))) short;
using f32x4  = __attribute__((ext_vector_type(4))) float;

__device__ __forceinline__ ushort_t f2bf(float x) {
    unsigned u = __float_as_uint(x);
    u = (u + 0x7FFFu + ((u >> 16) & 1u)) >> 16;   // RNE
    return (ushort_t)u;
}

// pack 2 floats -> 2 bf16 in one uint (v_cvt_pk_bf16_f32 on gfx950)
__device__ __forceinline__ unsigned pk2(float a, float b) {
    __hip_bfloat162 h = __float22bfloat162_rn(float2{a, b});
    unsigned u;
    __builtin_memcpy(&u, &h, 4);
    return u;
}

// async global->LDS, 16B per lane; LDS dest = wave-uniform base + lane*16
__device__ __forceinline__ void gll16(const ushort_t* g, ushort_t* l) {
    __builtin_amdgcn_global_load_lds(
        (const __attribute__((address_space(1))) void*)(g),
        (__attribute__((address_space(3))) void*)(l), 16, 0, 0);
}

// ---------------------------------------------------------------------------
// fp32 -> bf16 conversion, 7 tensors in one launch (blockIdx.y selects).
// ---------------------------------------------------------------------------
__global__ __launch_bounds__(256) void cvt_bf16(
    const float* s0, const float* s1, const float* s2, const float* s3,
    const float* s4, const float* s5, const float* s6,
    ushort_t* d0, ushort_t* d1, ushort_t* d2, ushort_t* d3,
    ushort_t* d4, ushort_t* d5, ushort_t* d6, int nIn, int nW)
{
    const float* s; ushort_t* d; int n;
    switch (blockIdx.y) {
        case 0: s = s0; d = d0; n = nIn; break;
        case 1: s = s1; d = d1; n = nIn; break;
        case 2: s = s2; d = d2; n = nIn; break;
        case 3: s = s3; d = d3; n = nW;  break;
        case 4: s = s4; d = d4; n = nW;  break;
        case 5: s = s5; d = d5; n = nW;  break;
        default: s = s6; d = d6; n = nW; break;
    }
    int i = (blockIdx.x * 256 + threadIdx.x) * 4;
    if (i < n) {
        float4 v = *(const float4*)&s[i];
        ushort4 o;
        o.x = f2bf(v.x); o.y = f2bf(v.y); o.z = f2bf(v.z); o.w = f2bf(v.w);
        *(ushort4*)&d[i] = o;
    }
}

// ---------------------------------------------------------------------------
// bf16 MFMA GEMM (QKV):  C[M,N] = (A @ W^T + bias) * oscale
// 128x128 tile, BK=64, SINGLE-buffered global_load_lds (r7 structure).
// MODE 0: bf16 row-major out.  MODE 1: bf16 transposed out [B*H][DK][SEQ].
// ---------------------------------------------------------------------------
struct GemmArgs { const ushort_t* A; const ushort_t* W; const float* bias;
                  void* C; int mode; float oscale; };

template<int MODE>
__device__ __forceinline__ void gemm_core(const GemmArgs& ga,
                                          ushort_t* As, ushort_t* Bs)
{
    constexpr bool SWP = (MODE != 1);
    const int tid  = threadIdx.x;
    const int w    = tid >> 6, lane = tid & 63;
    const int quad = lane >> 4, lx = lane & 15;
    const int mw = (w >> 1) * 64, nw = (w & 1) * 64;
    const int bm = blockIdx.x * 128, bn = blockIdx.y * 128;
    const int K = D_MODEL;

    f32x4 acc[4][4];
#pragma unroll
    for (int mt = 0; mt < 4; ++mt)
#pragma unroll
        for (int nt = 0; nt < 4; ++nt)
            acc[mt][nt] = (f32x4){0.f, 0.f, 0.f, 0.f};

    float4 b4[4];
    float  bfr[4];
#pragma unroll
    for (int nt = 0; nt < 4; ++nt) {
        if (SWP) b4[nt] = *(const float4*)&ga.bias[bn + nw + nt * 16 + quad * 4];
        else     bfr[nt] = ga.bias[bn + nw + nt * 16 + lx];
    }

    for (int k0 = 0; k0 < K; k0 += 64) {
        __syncthreads();
#pragma unroll
        for (int i = 0; i < 4; ++i) {
            int r0 = (w * 4 + i) * 8;
            int rl = r0 + (lane >> 3);
            int g  = (lane & 7) ^ (rl & 7);
            gll16(&ga.A[(size_t)(bm + rl) * K + k0 + g * 8], &As[r0 * 64]);
            gll16(&ga.W[(size_t)(bn + rl) * K + k0 + g * 8], &Bs[r0 * 64]);
        }
        __syncthreads();

#pragma unroll
        for (int ks = 0; ks < 2; ++ks) {
            short8 af[4], bf[4];
#pragma unroll
            for (int mt = 0; mt < 4; ++mt) {
                int r = mw + mt * 16 + lx;
                af[mt] = *(const short8*)&As[r * 64 + (((ks * 4 + quad) ^ (r & 7)) << 3)];
            }
#pragma unroll
            for (int nt = 0; nt < 4; ++nt) {
                int r = nw + nt * 16 + lx;
                bf[nt] = *(const short8*)&Bs[r * 64 + (((ks * 4 + quad) ^ (r & 7)) << 3)];
            }
#pragma unroll
            for (int mt = 0; mt < 4; ++mt)
#pragma unroll
                for (int nt = 0; nt < 4; ++nt)
                    acc[mt][nt] = SWP
                        ? __builtin_amdgcn_mfma_f32_16x16x32_bf16(bf[nt], af[mt], acc[mt][nt], 0, 0, 0)
                        : __builtin_amdgcn_mfma_f32_16x16x32_bf16(af[mt], bf[nt], acc[mt][nt], 0, 0, 0);
        }
    }

    if (MODE == 0) {
        ushort_t* C = (ushort_t*)ga.C;
        const float os = ga.oscale;
#pragma unroll
        for (int mt = 0; mt < 4; ++mt) {
            int m = bm + mw + mt * 16 + lx;
#pragma unroll
            for (int nt = 0; nt < 4; ++nt) {
                int n0 = bn + nw + nt * 16 + quad * 4;
                uint2 u;
                u.x = pk2((acc[mt][nt][0] + b4[nt].x) * os, (acc[mt][nt][1] + b4[nt].y) * os);
                u.y = pk2((acc[mt][nt][2] + b4[nt].z) * os, (acc[mt][nt][3] + b4[nt].w) * os);
                *(uint2*)&C[(size_t)m * D_MODEL + n0] = u;
            }
        }
    } else {
        ushort_t* C = (ushort_t*)ga.C;
#pragma unroll
        for (int mt = 0; mt < 4; ++mt)
#pragma unroll
            for (int nt = 0; nt < 4; ++nt) {
                int n = bn + nw + nt * 16 + lx;
                int d = n & 63, h = n >> 6;
                int m0 = bm + mw + mt * 16 + quad * 4;
                int b = m0 >> 11, s0 = m0 & 2047;
                uint2 u;
                u.x = pk2(acc[mt][nt][0] + bfr[nt], acc[mt][nt][1] + bfr[nt]);
                u.y = pk2(acc[mt][nt][2] + bfr[nt], acc[mt][nt][3] + bfr[nt]);
                *(uint2*)&C[((size_t)(b * NHEADS + h) * DK + d) * SEQ + s0] = u;
            }
    }
}

__global__ __launch_bounds__(256) void gemm_mfma(GemmArgs g0, GemmArgs g1, GemmArgs g2)
{
    __shared__ ushort_t As[128 * 64];
    __shared__ ushort_t Bs[128 * 64];
    GemmArgs ga = (blockIdx.z == 0) ? g0 : ((blockIdx.z == 1) ? g1 : g2);
    if (ga.mode == 0) gemm_core<0>(ga, As, Bs);
    else              gemm_core<1>(ga, As, Bs);
}

// ---------------------------------------------------------------------------
// O-projection GEMM: out[M,N] = Hc @ Wo^T + bo, fp32 out.
// ---------------------------------------------------------------------------
__global__ __launch_bounds__(256) void gemm_o(
    const ushort_t* __restrict__ A, const ushort_t* __restrict__ W,
    const float* __restrict__ bias, float* __restrict__ C)
{
    __shared__ ushort_t As[64 * 64];
    __shared__ ushort_t Bs[128 * 64];

    const int tid  = threadIdx.x;
    const int w    = tid >> 6, lane = tid & 63;
    const int quad = lane >> 4, lx = lane & 15;
    const int mw = (w >> 1) * 32, nw = (w & 1) * 64;
    const int bm = blockIdx.x * 64, bn = blockIdx.y * 128;
    const int K = D_MODEL;

    f32x4 acc[2][4];
#pragma unroll
    for (int mt = 0; mt < 2; ++mt)
#pragma unroll
        for (int nt = 0; nt < 4; ++nt)
            acc[mt][nt] = (f32x4){0.f, 0.f, 0.f, 0.f};

    float4 b4[4];
#pragma unroll
    for (int nt = 0; nt < 4; ++nt)
        b4[nt] = *(const float4*)&bias[bn + nw + nt * 16 + quad * 4];

    for (int k0 = 0; k0 < K; k0 += 64) {
        __syncthreads();
#pragma unroll
        for (int i = 0; i < 2; ++i) {
            int r0 = (i * 4 + w) * 8;
            int rl = r0 + (lane >> 3);
            int g  = (lane & 7) ^ (rl & 7);
            gll16(&A[(size_t)(bm + rl) * K + k0 + g * 8], &As[r0 * 64]);
        }
#pragma unroll
        for (int i = 0; i < 4; ++i) {
            int r0 = (i * 4 + w) * 8;
            int rl = r0 + (lane >> 3);
            int g  = (lane & 7) ^ (rl & 7);
            gll16(&W[(size_t)(bn + rl) * K + k0 + g * 8], &Bs[r0 * 64]);
        }
        __syncthreads();

#pragma unroll
        for (int ks = 0; ks < 2; ++ks) {
            short8 af[2], bf[4];
#pragma unroll
            for (int mt = 0; mt < 2; ++mt) {
                int r = mw + mt * 16 + lx;
                af[mt] = *(const short8*)&As[r * 64 + (((ks * 4 + quad) ^ (r & 7)) << 3)];
            }
#pragma unroll
            for (int nt = 0; nt < 4; ++nt) {
                int r = nw + nt * 16 + lx;
                bf[nt] = *(const short8*)&Bs[r * 64 + (((ks * 4 + quad) ^ (r & 7)) << 3)];
            }
#pragma unroll
            for (int mt = 0; mt < 2; ++mt)
#pragma unroll
                for (int nt = 0; nt < 4; ++nt)
                    acc[mt][nt] = __builtin_amdgcn_mfma_f32_16x16x32_bf16(
                        bf[nt], af[mt], acc[mt][nt], 0, 0, 0);
        }
    }

#pragma unroll
    for (int mt = 0; mt < 2; ++mt) {
        int m = bm + mw + mt * 16 + lx;
#pragma unroll
        for (int nt = 0; nt < 4; ++nt) {
            int n0 = bn + nw + nt * 16 + quad * 4;
            float4 v;
            v.x = acc[mt][nt][0] + b4[nt].x;
            v.y = acc[mt][nt][1] + b4[nt].y;
            v.z = acc[mt][nt][2] + b4[nt].z;
            v.w = acc[mt][nt][3] + b4[nt].w;
            *(float4*)&C[(size_t)m * D_MODEL + n0] = v;
        }
    }
}

// ---------------------------------------------------------------------------
// bf16 MFMA causal flash attention.
// r11 change vs r10: the kernel is LDS-read-pipe bound (arithmetic: 18
// b128-reads/wave-iter x 4 waves x 33792 iters ~= 33.5M LDS cycles / 256 CU
// ~= dispatch duration). Fix: QBLK 64->128 — each wave owns TWO 16-row
// q-groups (mt=0,1), so every K-frag / V-frag ds_read feeds 2x the MFMA
// math (frag addresses are q-independent). LDS traffic per unit math drops
// ~1.7x. Grid: 512 blocks (16 q-tiles x 32 bh), 2/CU, 4 bh/XCD (K/V 2MB,
// L2-fit). Per-CU pairing (qt=u, 15-u) balances totals. r10's rotation
// pipeline reverted (measured neutral — LDS pipe was the limiter).
// ---------------------------------------------------------------------------
__device__ __forceinline__ void flash_tile(
    int qt, const size_t qbase, const size_t vbase,
    const ushort_t* __restrict__ Qp, const ushort_t* __restrict__ Kp,
    const ushort_t* __restrict__ Vt, ushort_t* __restrict__ Hc,
    ushort_t* Ks0, ushort_t* Ks1, ushort_t* Vs0, ushort_t* Vs1,
    ushort_t (*Ps)[16 * 64])
{
    const int tid  = threadIdx.x;
    const int w    = tid >> 6, lane = tid & 63;
    const int quad = lane >> 4, lx = lane & 15;
    const int ktlast = 2 * qt + 1;

    // prologue: stage K(0), V(0) into buffer 0
#pragma unroll
    for (int i = 0; i < 2; ++i) {
        int r0 = (w + i * 4) * 8;
        int rl = r0 + (lane >> 3);
        int g  = (lane & 7) ^ (rl & 7);
        gll16(&Kp[qbase + (size_t)rl * D_MODEL + g * 8], &Ks0[r0 * 64]);
        gll16(&Vt[vbase + (size_t)rl * SEQ + g * 8], &Vs0[r0 * 64]);
    }

    // Q fragments for both 64-row halves (rows qt*128 + mt*64 + w*16 + lx)
    short8 qf0[2], qf1[2];
    {
        size_t ro = qbase + (size_t)(qt * 128 + w * 16 + lx) * D_MODEL + quad * 8;
        qf0[0] = *(const short8*)&Qp[ro];
        qf0[1] = *(const short8*)&Qp[ro + 32];
        qf1[0] = *(const short8*)&Qp[ro + (size_t)64 * D_MODEL];
        qf1[1] = *(const short8*)&Qp[ro + (size_t)64 * D_MODEL + 32];
    }

    // per-wave P row base: pad-free 128B rows, XOR-16B swizzle on (lx&7)
    char* Pb = (char*)&Ps[w][0] + (lx << 7);
    const int hsw = (lx & 7) << 4;

    f32x4 O0[4], O1[4];   // O^T frags per half: d = nt*16+quad*4+r, q = lx
#pragma unroll
    for (int nt = 0; nt < 4; ++nt) {
        O0[nt] = (f32x4){0.f, 0.f, 0.f, 0.f};
        O1[nt] = (f32x4){0.f, 0.f, 0.f, 0.f};
    }
    float m0 = -INFINITY, l0 = 0.f, m1 = -INFINITY, l1 = 0.f;
    const int qd = w * 16 + lx;   // q index within each 64-row half

    for (int kt = 0; kt <= ktlast; ++kt) {
        ushort_t* Ks = (kt & 1) ? Ks1 : Ks0;
        ushort_t* Vs = (kt & 1) ? Vs1 : Vs0;

        // tile-kt loads were issued one full iteration ago
        asm volatile("s_waitcnt vmcnt(0)" ::: "memory");
        asm volatile("s_barrier" ::: "memory");

        // prefetch k-tile kt+1 into the other buffer (overlaps compute below)
        if (kt < ktlast) {
            ushort_t* Kn = (kt & 1) ? Ks0 : Ks1;
            ushort_t* Vn = (kt & 1) ? Vs0 : Vs1;
#pragma unroll
            for (int i = 0; i < 2; ++i) {
                int r0 = (w + i * 4) * 8;
                int rl = r0 + (lane >> 3);
                int g  = (lane & 7) ^ (rl & 7);
                gll16(&Kp[qbase + (size_t)((kt + 1) * 64 + rl) * D_MODEL + g * 8], &Kn[r0 * 64]);
                gll16(&Vt[vbase + (size_t)rl * SEQ + (kt + 1) * 64 + g * 8], &Vn[r0 * 64]);
            }
        }

        const bool a0 = (kt < ktlast);   // mt0 half active (its k <= q range)

        // S^T = K Q^T for both halves; one K-frag read feeds both
        f32x4 s0[4], s1[4];
        __builtin_amdgcn_s_setprio(1);
        if (a0) {
#pragma unroll
            for (int nt = 0; nt < 4; ++nt) {
                int r = nt * 16 + lx;
                short8 kf0 = *(const short8*)&Ks[r * 64 + ((quad ^ (r & 7)) << 3)];
                short8 kf1 = *(const short8*)&Ks[r * 64 + (((4 + quad) ^ (r & 7)) << 3)];
                f32x4 z = (f32x4){0.f, 0.f, 0.f, 0.f};
                z = __builtin_amdgcn_mfma_f32_16x16x32_bf16(kf0, qf0[0], z, 0, 0, 0);
                z = __builtin_amdgcn_mfma_f32_16x16x32_bf16(kf1, qf0[1], z, 0, 0, 0);
                s0[nt] = z;
                f32x4 y = (f32x4){0.f, 0.f, 0.f, 0.f};
                y = __builtin_amdgcn_mfma_f32_16x16x32_bf16(kf0, qf1[0], y, 0, 0, 0);
                y = __builtin_amdgcn_mfma_f32_16x16x32_bf16(kf1, qf1[1], y, 0, 0, 0);
                s1[nt] = y;
            }
        } else {
#pragma unroll
            for (int nt = 0; nt < 4; ++nt) {
                int r = nt * 16 + lx;
                short8 kf0 = *(const short8*)&Ks[r * 64 + ((quad ^ (r & 7)) << 3)];
                short8 kf1 = *(const short8*)&Ks[r * 64 + (((4 + quad) ^ (r & 7)) << 3)];
                f32x4 y = (f32x4){0.f, 0.f, 0.f, 0.f};
                y = __builtin_amdgcn_mfma_f32_16x16x32_bf16(kf0, qf1[0], y, 0, 0, 0);
                y = __builtin_amdgcn_mfma_f32_16x16x32_bf16(kf1, qf1[1], y, 0, 0, 0);
                s1[nt] = y;
            }
        }
        __builtin_amdgcn_s_setprio(0);

        // causal masks: mt0 diagonal at kt == 2*qt, mt1 diagonal at ktlast
        if (a0 && kt == 2 * qt) {
#pragma unroll
            for (int nt = 0; nt < 4; ++nt)
#pragma unroll
                for (int r = 0; r < 4; ++r)
                    if ((nt * 16 + quad * 4 + r) > qd) s0[nt][r] = -INFINITY;
        }
        if (kt == ktlast) {
#pragma unroll
            for (int nt = 0; nt < 4; ++nt)
#pragma unroll
                for (int r = 0; r < 4; ++r)
                    if ((nt * 16 + quad * 4 + r) > qd) s1[nt][r] = -INFINITY;
        }

        // ---- online softmax, half 0 ----
        if (a0) {
            float a = fmaxf(fmaxf(s0[0][0], s0[0][1]), fmaxf(s0[0][2], s0[0][3]));
            float b = fmaxf(fmaxf(s0[1][0], s0[1][1]), fmaxf(s0[1][2], s0[1][3]));
            float c = fmaxf(fmaxf(s0[2][0], s0[2][1]), fmaxf(s0[2][2], s0[2][3]));
            float d = fmaxf(fmaxf(s0[3][0], s0[3][1]), fmaxf(s0[3][2], s0[3][3]));
            float tm = fmaxf(fmaxf(a, b), fmaxf(c, d));
            tm = fmaxf(tm, __shfl_xor(tm, 16, 64));
            tm = fmaxf(tm, __shfl_xor(tm, 32, 64));
            if (__any(tm > m0 + 8.f)) {
                float mnew = fmaxf(m0, tm);
                float alpha = __builtin_amdgcn_exp2f(m0 - mnew);
                m0 = mnew;
                l0 *= alpha;
#pragma unroll
                for (int nt = 0; nt < 4; ++nt)
#pragma unroll
                    for (int r = 0; r < 4; ++r) O0[nt][r] *= alpha;
            }
#pragma unroll
            for (int nt = 0; nt < 4; ++nt)
#pragma unroll
                for (int r = 0; r < 4; ++r)
                    s0[nt][r] = __builtin_amdgcn_exp2f(s0[nt][r] - m0);
            float r0s = (s0[0][0] + s0[0][1]) + (s0[0][2] + s0[0][3]);
            float r1s = (s0[1][0] + s0[1][1]) + (s0[1][2] + s0[1][3]);
            float r2s = (s0[2][0] + s0[2][1]) + (s0[2][2] + s0[2][3]);
            float r3s = (s0[3][0] + s0[3][1]) + (s0[3][2] + s0[3][3]);
            float rs = (r0s + r1s) + (r2s + r3s);
            rs += __shfl_xor(rs, 16, 64);
            rs += __shfl_xor(rs, 32, 64);
            l0 += rs;
        }

        // ---- online softmax, half 1 ----
        {
            float a = fmaxf(fmaxf(s1[0][0], s1[0][1]), fmaxf(s1[0][2], s1[0][3]));
            float b = fmaxf(fmaxf(s1[1][0], s1[1][1]), fmaxf(s1[1][2], s1[1][3]));
            float c = fmaxf(fmaxf(s1[2][0], s1[2][1]), fmaxf(s1[2][2], s1[2][3]));
            float d = fmaxf(fmaxf(s1[3][0], s1[3][1]), fmaxf(s1[3][2], s1[3][3]));
            float tm = fmaxf(fmaxf(a, b), fmaxf(c, d));
            tm = fmaxf(tm, __shfl_xor(tm, 16, 64));
            tm = fmaxf(tm, __shfl_xor(tm, 32, 64));
            if (__any(tm > m1 + 8.f)) {
                float mnew = fmaxf(m1, tm);
                float alpha = __builtin_amdgcn_exp2f(m1 - mnew);
                m1 = mnew;
                l1 *= alpha;
#pragma unroll
                for (int nt = 0; nt < 4; ++nt)
#pragma unroll
                    for (int r = 0; r < 4; ++r) O1[nt][r] *= alpha;
            }
#pragma unroll
            for (int nt = 0; nt < 4; ++nt)
#pragma unroll
                for (int r = 0; r < 4; ++r)
                    s1[nt][r] = __builtin_amdgcn_exp2f(s1[nt][r] - m1);
            float r0s = (s1[0][0] + s1[0][1]) + (s1[0][2] + s1[0][3]);
            float r1s = (s1[1][0] + s1[1][1]) + (s1[1][2] + s1[1][3]);
            float r2s = (s1[2][0] + s1[2][1]) + (s1[2][2] + s1[2][3]);
            float r3s = (s1[3][0] + s1[3][1]) + (s1[3][2] + s1[3][3]);
            float rs = (r0s + r1s) + (r2s + r3s);
            rs += __shfl_xor(rs, 16, 64);
            rs += __shfl_xor(rs, 32, 64);
            l1 += rs;
        }

        // P round-trips through per-wave LDS (same buffer reused for both
        // halves; DS pipe is in-order per wave so read-then-overwrite is safe)
        short8 pf00, pf01, pf10, pf11;
        if (a0) {
#pragma unroll
            for (int nt = 0; nt < 4; ++nt) {
                uint2 u;
                u.x = pk2(s0[nt][0], s0[nt][1]);
                u.y = pk2(s0[nt][2], s0[nt][3]);
                *(uint2*)(Pb + ((nt * 32 + quad * 8) ^ hsw)) = u;
            }
            pf00 = *(const short8*)(Pb + ((quad * 16) ^ hsw));
            pf01 = *(const short8*)(Pb + ((64 + quad * 16) ^ hsw));
        }
#pragma unroll
        for (int nt = 0; nt < 4; ++nt) {
            uint2 u;
            u.x = pk2(s1[nt][0], s1[nt][1]);
            u.y = pk2(s1[nt][2], s1[nt][3]);
            *(uint2*)(Pb + ((nt * 32 + quad * 8) ^ hsw)) = u;
        }
        pf10 = *(const short8*)(Pb + ((quad * 16) ^ hsw));
        pf11 = *(const short8*)(Pb + ((64 + quad * 16) ^ hsw));

        // O^T += V^T-frag x P-frag; one V-frag read feeds both halves
        __builtin_amdgcn_s_setprio(1);
        if (a0) {
#pragma unroll
            for (int nt = 0; nt < 4; ++nt) {
                int r = nt * 16 + lx;
                short8 vf0 = *(const short8*)&Vs[r * 64 + ((quad ^ (r & 7)) << 3)];
                short8 vf1 = *(const short8*)&Vs[r * 64 + (((4 + quad) ^ (r & 7)) << 3)];
                O0[nt] = __builtin_amdgcn_mfma_f32_16x16x32_bf16(vf0, pf00, O0[nt], 0, 0, 0);
                O0[nt] = __builtin_amdgcn_mfma_f32_16x16x32_bf16(vf1, pf01, O0[nt], 0, 0, 0);
                O1[nt] = __builtin_amdgcn_mfma_f32_16x16x32_bf16(vf0, pf10, O1[nt], 0, 0, 0);
                O1[nt] = __builtin_amdgcn_mfma_f32_16x16x32_bf16(vf1, pf11, O1[nt], 0, 0, 0);
            }
        } else {
#pragma unroll
            for (int nt = 0; nt < 4; ++nt) {
                int r = nt * 16 + lx;
                short8 vf0 = *(const short8*)&Vs[r * 64 + ((quad ^ (r & 7)) << 3)];
                short8 vf1 = *(const short8*)&Vs[r * 64 + (((4 + quad) ^ (r & 7)) << 3)];
                O1[nt] = __builtin_amdgcn_mfma_f32_16x16x32_bf16(vf0, pf10, O1[nt], 0, 0, 0);
                O1[nt] = __builtin_amdgcn_mfma_f32_16x16x32_bf16(vf1, pf11, O1[nt], 0, 0, 0);
            }
        }
        __builtin_amdgcn_s_setprio(0);
    }

    // epilogue: lane writes row q, 4 consecutive d per nt (b64 stores)
    {
        float invl = 1.f / l0;
        size_t ro = qbase + (size_t)(qt * 128 + w * 16 + lx) * D_MODEL;
#pragma unroll
        for (int nt = 0; nt < 4; ++nt) {
            uint2 u;
            u.x = pk2(O0[nt][0] * invl, O0[nt][1] * invl);
            u.y = pk2(O0[nt][2] * invl, O0[nt][3] * invl);
            *(uint2*)&Hc[ro + nt * 16 + quad * 4] = u;
        }
        invl = 1.f / l1;
        ro += (size_t)64 * D_MODEL;
#pragma unroll
        for (int nt = 0; nt < 4; ++nt) {
            uint2 u;
            u.x = pk2(O1[nt][0] * invl, O1[nt][1] * invl);
            u.y = pk2(O1[nt][2] * invl, O1[nt][3] * invl);
            *(uint2*)&Hc[ro + nt * 16 + quad * 4] = u;
        }
    }
}

__global__ __launch_bounds__(256) void flash_mfma(
    const ushort_t* __restrict__ Qp, const ushort_t* __restrict__ Kp,
    const ushort_t* __restrict__ Vt, ushort_t* __restrict__ Hc)
{
    __shared__ ushort_t Ks0[64 * 64], Ks1[64 * 64];
    __shared__ ushort_t Vs0[64 * 64], Vs1[64 * 64];
    __shared__ __align__(16) ushort_t Ps[4][16 * 64];   // total LDS = 40960B

    // 512 blocks. XCD c gets bh in {c, c+8, c+16, c+24} (K/V 2MB, L2-fit);
    // per-CU slot pair gets qt = {u, 15-u} -> 34 k-iters per CU, balanced.
    const int flat = blockIdx.x;          // 0..511
    const int c  = flat & 7;              // XCD
    const int j  = flat >> 3;             // 0..63 within XCD
    const int cu = j & 31;                // CU slot heuristic
    const int m  = j >> 5;                // 0..1 co-residency slot
    const int bh = c + ((cu >> 3) << 3);  // 4 heads per XCD
    const int u  = cu & 7;
    const int qt = m ? (NQT2 - 1 - u) : u;
    const int b = bh >> 4, h = bh & 15;

    const size_t qbase = (size_t)(b * SEQ) * D_MODEL + h * DK;
    const size_t vbase = (size_t)bh * DK * SEQ;

    flash_tile(qt, qbase, vbase, Qp, Kp, Vt, Hc, Ks0, Ks1, Vs0, Vs1, Ps);
}

extern "C" void kernel_launch(void* const* d_in, const int* in_sizes, int n_in,
                              void* d_out, int out_size, void* d_ws, size_t ws_size,
                              hipStream_t stream) {
    const float* inQ = (const float*)d_in[0];
    const float* inK = (const float*)d_in[1];
    const float* inV = (const float*)d_in[2];
    const float* Wq  = (const float*)d_in[3];
    const float* bq  = (const float*)d_in[4];
    const float* Wk  = (const float*)d_in[5];
    const float* bk  = (const float*)d_in[6];
    const float* Wv  = (const float*)d_in[7];
    const float* bv  = (const float*)d_in[8];
    const float* Wo  = (const float*)d_in[9];
    const float* bo  = (const float*)d_in[10];
    float* out = (float*)d_out;

    const size_t NI = (size_t)MROWS * D_MODEL;      // 4M
    const size_t NW = (size_t)D_MODEL * D_MODEL;    // 1M
    ushort_t* ws  = (ushort_t*)d_ws;
    ushort_t* Qb  = ws;                // bf16 inputs
    ushort_t* Kb  = Qb  + NI;
    ushort_t* Vb  = Kb  + NI;
    ushort_t* Wqb = Vb  + NI;          // bf16 weights
    ushort_t* Wkb = Wqb + NW;
    ushort_t* Wvb = Wkb + NW;
    ushort_t* Wob = Wvb + NW;
    ushort_t* Qp  = Wob + NW;          // projections
    ushort_t* Kp  = Qp  + NI;
    ushort_t* Vtg = Kp  + NI;          // V^T [B*H][DK][SEQ]
    ushort_t* Hc  = Vtg + NI;

    // fp32 -> bf16 (all 7 tensors, one launch)
    cvt_bf16<<<dim3(NI / 1024, 7), 256, 0, stream>>>(
        inQ, inK, inV, Wq, Wk, Wv, Wo,
        Qb, Kb, Vb, Wqb, Wkb, Wvb, Wob, (int)NI, (int)NW);

    // fused QKV projection; Q pre-scaled by 1/sqrt(dk)*log2(e); V transposed
    const float qsc = 0.125f * 1.44269504088896340736f;
    GemmArgs aq{Qb, Wqb, bq, (void*)Qp, 0, qsc};
    GemmArgs ak{Kb, Wkb, bk, (void*)Kp, 0, 1.0f};
    GemmArgs av{Vb, Wvb, bv, (void*)Vtg, 1, 1.0f};
    gemm_mfma<<<dim3(MROWS / 128, D_MODEL / 128, 3), 256, 0, stream>>>(aq, ak, av);

    // attention: 128-row q-tiles, 512 blocks (2/CU), XCD-grouped
    flash_mfma<<<dim3(NQT2 * BATCH * NHEADS), 256, 0, stream>>>(Qp, Kp, Vtg, Hc);

    // output projection (fp32 out), 64x128 single-buffer tiles, 512 blocks
    gemm_o<<<dim3(MROWS / 64, D_MODEL / 128), 256, 0, stream>>>(Hc, Wob, bo, out);
}